// Round 1
// baseline (23510.838 us; speedup 1.0000x reference)
//
#include <hip/hip_runtime.h>
#include <math.h>

#define BATCH 128
#define SEQ 512
#define HID 512
#define BH (BATCH*HID)            // 65536
#define NGROUP 4                  // independent batch groups (32 batches each)
#define GBATCH 32
#define CPB 8                     // HID cols per block
#define NCOLBLK (HID/CPB)         // 64 blocks per group
#define NBLOCKS (NGROUP*NCOLBLK)  // 256 blocks total -> guaranteed co-resident
#define WT_FLOATS (512*512*4)     // transposed weights [k4][n][kk][gate]
#define BARMEM 64                 // ints per group's barrier region (256 B)

// ws layout (floats): [0,2*BH) H ping-pong | [2*BH, 2*BH+WT_FLOATS) Wt | then barrier ints

__device__ __forceinline__ void group_barrier(int* gen, int* cnt, int members) {
    __syncthreads();               // all block threads done with this step's loads+stores
    if (threadIdx.x == 0) {
        __threadfence();           // release: make our H_new stores visible device-wide
        int g = __hip_atomic_load(gen, __ATOMIC_RELAXED, __HIP_MEMORY_SCOPE_AGENT);
        int prev = __hip_atomic_fetch_add(cnt, 1, __ATOMIC_ACQ_REL, __HIP_MEMORY_SCOPE_AGENT);
        if (prev == members - 1) {
            __hip_atomic_store(cnt, 0, __ATOMIC_RELAXED, __HIP_MEMORY_SCOPE_AGENT);
            __hip_atomic_store(gen, g + 1, __ATOMIC_RELEASE, __HIP_MEMORY_SCOPE_AGENT);
        } else {
            while (__hip_atomic_load(gen, __ATOMIC_RELAXED, __HIP_MEMORY_SCOPE_AGENT) == g) {
                __builtin_amdgcn_s_sleep(1);
            }
        }
        __threadfence();           // acquire: invalidate stale L1/L2 before next step's reads
    }
    __syncthreads();
}

// One-shot per-call init: build interleaved weight layout, copy H0 into ping buffer,
// zero barrier state (d_ws is re-poisoned to 0xAA before every replay).
__global__ void lstm_init(const float* __restrict__ H0,
                          const float* __restrict__ Wi, const float* __restrict__ Wf,
                          const float* __restrict__ Wc, const float* __restrict__ Wo,
                          float* __restrict__ ws) {
    int idx = blockIdx.x * blockDim.x + threadIdx.x;
    float* hbuf = ws;
    float* Wt   = ws + 2*BH;
    int*   bar  = (int*)(ws + 2*BH + WT_FLOATS);
    if (idx < WT_FLOATS) {
        // dst flat: ((k4*512 + n)*4 + kk)*4 + g   (k = 4*k4+kk, gate g)
        int g  = idx & 3;
        int kk = (idx >> 2) & 3;
        int n  = (idx >> 4) & 511;
        int k4 = idx >> 13;
        int k  = 4*k4 + kk;
        const float* W = (g == 0) ? Wi : (g == 1) ? Wf : (g == 2) ? Wc : Wo;
        Wt[idx] = W[(k + 1)*512 + n];   // rows 1..512 are the H weights
    }
    int j = idx - WT_FLOATS;
    if (j >= 0 && j < BH) hbuf[j] = H0[j];
    int m = j - BH;
    if (m >= 0 && m < NGROUP*BARMEM) bar[m] = 0;
}

__global__ __launch_bounds__(256, 1)
void lstm_main(const float* __restrict__ x,
               const float* __restrict__ C0,
               const float* __restrict__ Wi, const float* __restrict__ bi,
               const float* __restrict__ Wf, const float* __restrict__ bf_,
               const float* __restrict__ Wc, const float* __restrict__ bc,
               const float* __restrict__ Wo, const float* __restrict__ bo,
               float* __restrict__ out, float* __restrict__ ws) {
    float* hbuf     = ws;
    const float* Wt = ws + 2*BH;
    int*   bar      = (int*)(ws + 2*BH + WT_FLOATS);

    const int bid    = blockIdx.x;
    const int g      = bid & 3;        // batch group; %4 keeps group on ~2 XCDs
    const int colblk = bid >> 2;       // 0..63
    const int tid    = threadIdx.x;
    const int cc     = tid & 7;        // col within block
    const int brow   = tid >> 3;       // 0..31 batch within group
    const int b      = g*GBATCH + brow;
    const int c      = colblk*CPB + cc;

    int* ggen = bar + g*BARMEM;
    int* gcnt = bar + g*BARMEM + 32;   // separate 128B line from gen

    // Per-thread constants: biases + row-0 (x) weights + C state in registers.
    const float bias_i = bi[c],  bias_f = bf_[c], bias_c = bc[c], bias_o = bo[c];
    const float w0i = Wi[c], w0f = Wf[c], w0c = Wc[c], w0o = Wo[c];
    float C = C0[b*HID + c];

    const float* wbase = Wt + (size_t)c * 16;   // + k4*8192 floats per k-quad
    const float* xrow  = x + b*SEQ;

    int rofs = 0;                               // read half of ping-pong
    for (int t = 0; t < SEQ; ++t) {
        float xv = xrow[t];
        float ai = fmaf(xv, w0i, bias_i);
        float af = fmaf(xv, w0f, bias_f);
        float ag = fmaf(xv, w0c, bias_c);
        float ao = fmaf(xv, w0o, bias_o);
        const float4* hp = (const float4*)(hbuf + rofs + b*HID);
        #pragma unroll 4
        for (int k4 = 0; k4 < 128; ++k4) {
            float4 h4 = hp[k4];                                  // 4 H values (L1-hit)
            const float4* w = (const float4*)(wbase + (size_t)k4*8192);
            float4 w0 = w[0], w1 = w[1], w2 = w[2], w3 = w[3];   // 64B contiguous/lane
            ai = fmaf(h4.x, w0.x, ai); af = fmaf(h4.x, w0.y, af);
            ag = fmaf(h4.x, w0.z, ag); ao = fmaf(h4.x, w0.w, ao);
            ai = fmaf(h4.y, w1.x, ai); af = fmaf(h4.y, w1.y, af);
            ag = fmaf(h4.y, w1.z, ag); ao = fmaf(h4.y, w1.w, ao);
            ai = fmaf(h4.z, w2.x, ai); af = fmaf(h4.z, w2.y, af);
            ag = fmaf(h4.z, w2.z, ag); ao = fmaf(h4.z, w2.w, ao);
            ai = fmaf(h4.w, w3.x, ai); af = fmaf(h4.w, w3.y, af);
            ag = fmaf(h4.w, w3.z, ag); ao = fmaf(h4.w, w3.w, ao);
        }
        float I  = 1.0f / (1.0f + expf(-ai));
        float F  = 1.0f / (1.0f + expf(-af));
        float Ch = tanhf(ag);
        C = fmaf(F, C, I*Ch);
        float Hn = ao * tanhf(C);      // reference: O has NO sigmoid
        if (t == SEQ - 1) {
            int o = b*HID + c;
            out[o] = Hn; out[BH + o] = Hn; out[2*BH + o] = C;
        } else {
            hbuf[(rofs ^ BH) + b*HID + c] = Hn;
            group_barrier(ggen, gcnt, NCOLBLK);
        }
        rofs ^= BH;
    }
}

extern "C" void kernel_launch(void* const* d_in, const int* in_sizes, int n_in,
                              void* d_out, int out_size, void* d_ws, size_t ws_size,
                              hipStream_t stream) {
    const float* x  = (const float*)d_in[0];
    const float* H0 = (const float*)d_in[1];
    const float* C0 = (const float*)d_in[2];
    const float* Wi = (const float*)d_in[3];
    const float* bi = (const float*)d_in[4];
    const float* Wf = (const float*)d_in[5];
    const float* bf = (const float*)d_in[6];
    const float* Wc = (const float*)d_in[7];
    const float* bc = (const float*)d_in[8];
    const float* Wo = (const float*)d_in[9];
    const float* bo = (const float*)d_in[10];
    float* out = (float*)d_out;
    float* ws  = (float*)d_ws;   // needs ~4.6 MB: 512KB H ping-pong + 4MB Wt + 1KB barrier

    const int init_elems = WT_FLOATS + BH + NGROUP*BARMEM;
    hipLaunchKernelGGL(lstm_init, dim3((init_elems + 255)/256), dim3(256), 0, stream,
                       H0, Wi, Wf, Wc, Wo, ws);
    hipLaunchKernelGGL(lstm_main, dim3(NBLOCKS), dim3(256), 0, stream,
                       x, C0, Wi, bi, Wf, bf, Wc, bc, Wo, bo, out, ws);
}